// Round 1
// baseline (588.120 us; speedup 1.0000x reference)
//
#include <hip/hip_runtime.h>
#include <hip/hip_bf16.h>

// Problem constants (fixed by the reference)
#define BATCH 8
#define NPTS  4096      // N
#define CCH   128       // C
#define KNN_K 16        // K

typedef __attribute__((ext_vector_type(8))) short  bf16x8;  // 8 bf16 = 4 VGPRs
typedef __attribute__((ext_vector_type(4))) float  f32x4;   // MFMA acc

// ---------------------------------------------------------------------------
// ws layout (bytes):
//   [0)          xTb   : B*N*C bf16      = 8,388,608
//   [8388608)    Wb    : C*C  bf16       =    32,768
//   [8421376)    scale : C fp32          =       512
//   [8421888)    bias  : C fp32          =       512
//   [8422400)    pts   : B*N float4(x,y,z,s) = 524,288
//   [8946688)    knn   : B*N*K u16       = 1,048,576
// total ~9.53 MB
// ---------------------------------------------------------------------------

static __device__ __forceinline__ short f2bf(float v) {
    __hip_bfloat16 h = __float2bfloat16(v);   // RNE
    return __builtin_bit_cast(short, h);
}

// Prep: x [B,C,N] fp32 -> xT [B,N,C] bf16; W -> bf16; fold BN affine; xyz -> SoA float4
__global__ __launch_bounds__(256) void prep_kernel(
    const float* __restrict__ x, const float* __restrict__ xyz,
    const float* __restrict__ W, const float* __restrict__ gamma,
    const float* __restrict__ beta, const float* __restrict__ rmean,
    const float* __restrict__ rvar,
    short* __restrict__ xTb, short* __restrict__ Wb,
    float* __restrict__ scale, float* __restrict__ bias,
    float4* __restrict__ pts)
{
    const int t = blockIdx.x * 256 + threadIdx.x;   // grid covers exactly B*N*C
    {
        const int b   = t >> 19;            // N*C = 2^19
        const int rem = t & 524287;
        const int n   = rem >> 7;
        const int c   = rem & 127;
        xTb[t] = f2bf(x[(size_t)(b * CCH + c) * NPTS + n]);
    }
    if (t < CCH * CCH) Wb[t] = f2bf(W[t]);
    if (t < CCH) {
        const float s = gamma[t] / sqrtf(rvar[t] + 1e-5f);
        scale[t] = s;
        bias[t]  = beta[t] - rmean[t] * s;
    }
    if (t < BATCH * NPTS) {
        #pragma clang fp contract(off)
        const float px = xyz[3 * t + 0];
        const float py = xyz[3 * t + 1];
        const float pz = xyz[3 * t + 2];
        const float s  = px * px + py * py + pz * pz;   // matches ref s = sum(xyz*xyz)
        pts[t] = make_float4(px, py, pz, s);
    }
}

// Branchless unrolled insert into sorted-ascending top-16 (strict <: earlier j wins ties)
__device__ __forceinline__ void insert16(float bd[16], int bi[16], float d, int j) {
    #pragma unroll
    for (int t = 15; t >= 1; --t) {
        const bool ct  = d < bd[t];
        const bool ct1 = d < bd[t - 1];
        bd[t] = ct ? (ct1 ? bd[t - 1] : d) : bd[t];
        bi[t] = ct ? (ct1 ? bi[t - 1] : j) : bi[t];
    }
    if (d < bd[0]) { bd[0] = d; bi[0] = j; }
}

// KNN: block = 128 threads = 2 waves over the SAME 64 queries; wave w scans j-half.
// Per-lane 4-deep pending buffer + ballot-gated drain keeps the 16-slot chain rare.
__global__ __launch_bounds__(128) void knn_kernel(
    const float4* __restrict__ pts, unsigned short* __restrict__ knn)
{
    const int lane = threadIdx.x & 63;
    const int w    = threadIdx.x >> 6;
    const int b    = blockIdx.x >> 6;                  // 64 i-tiles per batch
    const int i    = ((blockIdx.x & 63) << 6) + lane;
    const float4* pb = pts + (b << 12);
    const float4 q = pb[i];

    float bd[16]; int bi[16];
    #pragma unroll
    for (int t = 0; t < 16; ++t) { bd[t] = 3.4e38f; bi[t] = 0; }

    float pd0 = 0, pd1 = 0, pd2 = 0, pd3 = 0;
    int   pj0 = 0, pj1 = 0, pj2 = 0, pj3 = 0, cnt = 0;

    const int jbeg = w << 11, jend = jbeg + 2048;
    for (int j = jbeg; j < jend; ++j) {
        #pragma clang fp contract(off)
        const float4 p  = pb[j];
        const float dot = q.x * p.x + q.y * p.y + q.z * p.z;
        const float d2  = (q.w + p.w) - 2.0f * dot;     // s_i + s_j - 2*dot, as reference
        const bool hit  = d2 < bd[15];
        if (__any(hit)) {
            if (hit) {
                pd3 = pd2; pj3 = pj2; pd2 = pd1; pj2 = pj1;
                pd1 = pd0; pj1 = pj0; pd0 = d2;  pj0 = j; ++cnt;
            }
            if (__any(cnt >= 4)) {          // drain oldest-first (ascending j => stable ties)
                if (cnt > 3) insert16(bd, bi, pd3, pj3);
                if (cnt > 2) insert16(bd, bi, pd2, pj2);
                if (cnt > 1) insert16(bd, bi, pd1, pj1);
                if (cnt > 0) insert16(bd, bi, pd0, pj0);
                cnt = 0;
            }
        }
    }
    if (cnt > 3) insert16(bd, bi, pd3, pj3);
    if (cnt > 2) insert16(bd, bi, pd2, pj2);
    if (cnt > 1) insert16(bd, bi, pd1, pj1);
    if (cnt > 0) insert16(bd, bi, pd0, pj0);

    __shared__ float          sbd[16][64];
    __shared__ unsigned short sbi[16][64];
    if (w == 1) {
        #pragma unroll
        for (int t = 0; t < 16; ++t) { sbd[t][lane] = bd[t]; sbi[t][lane] = (unsigned short)bi[t]; }
    }
    __syncthreads();
    if (w == 0) {
        // wave1's j's are all > wave0's: inserting after keeps earlier-index on ties
        #pragma unroll
        for (int t = 0; t < 16; ++t) insert16(bd, bi, sbd[t][lane], (int)sbi[t][lane]);
        unsigned short* o = knn + ((((size_t)b << 12) + i) << 4);
        #pragma unroll
        for (int t = 0; t < 16; ++t) o[t] = (unsigned short)bi[t];
    }
}

// Fused gather + GEMM(bf16 MFMA) + BN + ReLU + max-over-K.
// Wave handles 2 points; M-tile(16) = the 16 neighbors of one point, N = 128 outputs.
__global__ __launch_bounds__(256) void gemm_kernel(
    const short* __restrict__ xTb, const short* __restrict__ Wb,
    const unsigned short* __restrict__ knn,
    const float* __restrict__ scale, const float* __restrict__ bias,
    float* __restrict__ out)
{
    const int lane = threadIdx.x & 63;
    const int wid  = threadIdx.x >> 6;
    const int b    = blockIdx.x >> 9;            // N/8 = 512 groups per batch
    const int ng   = blockIdx.x & 511;
    const int n0   = ng * 8 + wid * 2;           // this wave's two points
    const int kl   = lane & 15;                  // A: m-index = neighbor k; B: n-index = out ch
    const int c0   = (lane >> 4) * 8;            // k-dim sub-offset within 32-chunk

    int rowoff[2];
    #pragma unroll
    for (int p = 0; p < 2; ++p) {
        const int n = n0 + p;
        const int r = (int)knn[(((size_t)b * NPTS + n) << 4) + kl];
        rowoff[p] = (b * NPTS + r) * CCH;        // element offset into xTb
    }

    const f32x4 zero = {0.f, 0.f, 0.f, 0.f};
    f32x4 acc[2][8];
    #pragma unroll
    for (int p = 0; p < 2; ++p)
        #pragma unroll
        for (int t = 0; t < 8; ++t) acc[p][t] = zero;

    #pragma unroll
    for (int kk = 0; kk < 4; ++kk) {             // K = 128 channels, 32 per MFMA
        const int cb = kk * 32 + c0;
        bf16x8 a0 = *(const bf16x8*)(xTb + rowoff[0] + cb);
        bf16x8 a1 = *(const bf16x8*)(xTb + rowoff[1] + cb);
        #pragma unroll
        for (int t = 0; t < 8; ++t) {
            const bf16x8 bf = *(const bf16x8*)(Wb + (t * 16 + kl) * CCH + cb);
            acc[0][t] = __builtin_amdgcn_mfma_f32_16x16x32_bf16(a0, bf, acc[0][t], 0, 0, 0);
            acc[1][t] = __builtin_amdgcn_mfma_f32_16x16x32_bf16(a1, bf, acc[1][t], 0, 0, 0);
        }
    }

    // Epilogue: BN + ReLU + max over the 16 rows (= neighbors) of each tile.
    #pragma unroll
    for (int t = 0; t < 8; ++t) {
        const int o = t * 16 + kl;
        const float s  = scale[o];
        const float bb = bias[o];
        #pragma unroll
        for (int p = 0; p < 2; ++p) {
            const f32x4 v = acc[p][t];
            float mx = 0.f;                      // relu floor: max_k relu(y) = max(0, max_k y)
            #pragma unroll
            for (int r = 0; r < 4; ++r) mx = fmaxf(mx, v[r] * s + bb);
            mx = fmaxf(mx, __shfl_xor(mx, 16));
            mx = fmaxf(mx, __shfl_xor(mx, 32));
            if (lane < 16) out[(size_t)(b * CCH + o) * NPTS + (n0 + p)] = mx;
        }
    }
}

extern "C" void kernel_launch(void* const* d_in, const int* in_sizes, int n_in,
                              void* d_out, int out_size, void* d_ws, size_t ws_size,
                              hipStream_t stream)
{
    const float* xyz   = (const float*)d_in[0];
    const float* x     = (const float*)d_in[1];
    const float* W     = (const float*)d_in[2];
    const float* gamma = (const float*)d_in[3];
    const float* beta  = (const float*)d_in[4];
    const float* rmean = (const float*)d_in[5];
    const float* rvar  = (const float*)d_in[6];
    float* out = (float*)d_out;

    char* ws = (char*)d_ws;
    short*          xTb   = (short*)(ws);
    short*          Wb    = (short*)(ws + 8388608);
    float*          scale = (float*)(ws + 8421376);
    float*          bias  = (float*)(ws + 8421888);
    float4*         pts   = (float4*)(ws + 8422400);
    unsigned short* knn   = (unsigned short*)(ws + 8946688);

    prep_kernel<<<BATCH * NPTS * CCH / 256, 256, 0, stream>>>(
        x, xyz, W, gamma, beta, rmean, rvar, xTb, Wb, scale, bias, pts);
    knn_kernel<<<BATCH * (NPTS / 64), 128, 0, stream>>>(pts, knn);
    gemm_kernel<<<BATCH * (NPTS / 8), 256, 0, stream>>>(xTb, Wb, knn, scale, bias, out);
}

// Round 2
// 384.734 us; speedup vs baseline: 1.5286x; 1.5286x over previous
//
#include <hip/hip_runtime.h>
#include <hip/hip_bf16.h>

// Problem constants (fixed by the reference)
#define BATCH 8
#define NPTS  4096      // N
#define CCH   128       // C
#define KNN_K 16        // K

typedef __attribute__((ext_vector_type(8))) short  bf16x8;  // 8 bf16 = 4 VGPRs
typedef __attribute__((ext_vector_type(4))) float  f32x4;   // MFMA acc

// ---------------------------------------------------------------------------
// ws layout (bytes):
//   [0)          xTb   : B*N*C bf16      = 8,388,608
//   [8388608)    Wb    : C*C  bf16       =    32,768
//   [8421376)    scale : C fp32          =       512
//   [8421888)    bias  : C fp32          =       512
//   [8422400)    pts   : B*N float4(x,y,z,s) = 524,288
//   [8946688)    knn   : B*N*K u16       = 1,048,576
// ---------------------------------------------------------------------------

static __device__ __forceinline__ short f2bf(float v) {
    __hip_bfloat16 h = __float2bfloat16(v);   // RNE
    return __builtin_bit_cast(short, h);
}

// LDS-tiled transpose: x [B,C,N] fp32 -> xTb [B,N,C] bf16.
// 64x64 tiles; read coalesced along n, write coalesced along c; pitch 66 kills
// the stride-64 bank conflict on the transposed read.
__global__ __launch_bounds__(256) void transpose_kernel(
    const float* __restrict__ x, short* __restrict__ xTb)
{
    __shared__ short tile[64 * 66];
    const int tid = threadIdx.x;
    const int b   = blockIdx.x >> 7;         // 8 batches
    const int rem = blockIdx.x & 127;
    const int nt  = rem >> 1;                // 64 n-tiles of 64
    const int ct  = rem & 1;                 // 2 c-tiles of 64

    #pragma unroll
    for (int it = 0; it < 16; ++it) {
        const int idx = it * 256 + tid;
        const int cc  = idx >> 6;
        const int nn  = idx & 63;
        const float v = x[(size_t)(b * CCH + ct * 64 + cc) * NPTS + nt * 64 + nn];
        tile[cc * 66 + nn] = f2bf(v);
    }
    __syncthreads();
    #pragma unroll
    for (int it = 0; it < 16; ++it) {
        const int idx = it * 256 + tid;
        const int nn  = idx >> 6;
        const int cc  = idx & 63;
        xTb[(size_t)(b * NPTS + nt * 64 + nn) * CCH + ct * 64 + cc] = tile[cc * 66 + nn];
    }
}

// Small prep: W -> bf16; fold BN affine; xyz -> SoA float4 with |p|^2
__global__ __launch_bounds__(256) void small_prep_kernel(
    const float* __restrict__ xyz, const float* __restrict__ W,
    const float* __restrict__ gamma, const float* __restrict__ beta,
    const float* __restrict__ rmean, const float* __restrict__ rvar,
    short* __restrict__ Wb, float* __restrict__ scale, float* __restrict__ bias,
    float4* __restrict__ pts)
{
    const int t = blockIdx.x * 256 + threadIdx.x;   // grid covers B*N = 32768
    if (t < CCH * CCH) Wb[t] = f2bf(W[t]);
    if (t < CCH) {
        const float s = gamma[t] / sqrtf(rvar[t] + 1e-5f);
        scale[t] = s;
        bias[t]  = beta[t] - rmean[t] * s;
    }
    {
        #pragma clang fp contract(off)
        const float px = xyz[3 * t + 0];
        const float py = xyz[3 * t + 1];
        const float pz = xyz[3 * t + 2];
        const float s  = px * px + py * py + pz * pz;   // matches ref s = sum(xyz*xyz)
        pts[t] = make_float4(px, py, pz, s);
    }
}

// Branchless unrolled insert into sorted-ascending top-16 (strict <: earlier j wins ties)
__device__ __forceinline__ void insert16(float bd[16], int bi[16], float d, int j) {
    #pragma unroll
    for (int t = 15; t >= 1; --t) {
        const bool ct  = d < bd[t];
        const bool ct1 = d < bd[t - 1];
        bd[t] = ct ? (ct1 ? bd[t - 1] : d) : bd[t];
        bi[t] = ct ? (ct1 ? bi[t - 1] : j) : bi[t];
    }
    if (d < bd[0]) { bd[0] = d; bi[0] = j; }
}

// KNN: block = 512 threads = 8 waves over the SAME 64 queries; wave w scans
// j in [w*512, (w+1)*512). Per-lane 4-deep pending buffer + ballot-gated drain.
// Tree-merge (8->4->2->1) through LDS; higher-j waves always merge INTO
// lower-j waves with strict <, preserving lowest-index tie-break.
__global__ __launch_bounds__(512) void knn_kernel(
    const float4* __restrict__ pts, unsigned short* __restrict__ knn)
{
    const int lane = threadIdx.x & 63;
    const int w    = threadIdx.x >> 6;                 // 0..7
    const int b    = blockIdx.x >> 6;                  // 64 i-tiles per batch
    const int i    = ((blockIdx.x & 63) << 6) + lane;
    const float4* pb = pts + (b << 12);
    const float4 q = pb[i];

    float bd[16]; int bi[16];
    #pragma unroll
    for (int t = 0; t < 16; ++t) { bd[t] = 3.4e38f; bi[t] = 0; }

    float pd0 = 0, pd1 = 0, pd2 = 0, pd3 = 0;
    int   pj0 = 0, pj1 = 0, pj2 = 0, pj3 = 0, cnt = 0;

    const int jbeg = w << 9, jend = jbeg + 512;
    for (int j = jbeg; j < jend; ++j) {
        #pragma clang fp contract(off)
        const float4 p  = pb[j];
        const float dot = q.x * p.x + q.y * p.y + q.z * p.z;
        const float d2  = (q.w + p.w) - 2.0f * dot;     // s_i + s_j - 2*dot, as reference
        const bool hit  = d2 < bd[15];
        if (__any(hit)) {
            if (hit) {
                pd3 = pd2; pj3 = pj2; pd2 = pd1; pj2 = pj1;
                pd1 = pd0; pj1 = pj0; pd0 = d2;  pj0 = j; ++cnt;
            }
            if (__any(cnt >= 4)) {          // drain oldest-first (ascending j => stable ties)
                if (cnt > 3) insert16(bd, bi, pd3, pj3);
                if (cnt > 2) insert16(bd, bi, pd2, pj2);
                if (cnt > 1) insert16(bd, bi, pd1, pj1);
                if (cnt > 0) insert16(bd, bi, pd0, pj0);
                cnt = 0;
            }
        }
    }
    if (cnt > 3) insert16(bd, bi, pd3, pj3);
    if (cnt > 2) insert16(bd, bi, pd2, pj2);
    if (cnt > 1) insert16(bd, bi, pd1, pj1);
    if (cnt > 0) insert16(bd, bi, pd0, pj0);

    // ---- tree merge through LDS: 4 publish slots of [16][64] ----
    __shared__ float          sbd[4][16][64];
    __shared__ unsigned short sbi[4][16][64];

    // Round A: odd waves publish, even waves consume partner (w+1, higher j)
    if (w & 1) {
        const int s = w >> 1;
        #pragma unroll
        for (int t = 0; t < 16; ++t) { sbd[s][t][lane] = bd[t]; sbi[s][t][lane] = (unsigned short)bi[t]; }
    }
    __syncthreads();
    if (!(w & 1)) {
        const int s = w >> 1;
        #pragma unroll
        for (int t = 0; t < 16; ++t) insert16(bd, bi, sbd[s][t][lane], (int)sbi[s][t][lane]);
    }
    __syncthreads();
    // Round B: waves 2,6 publish; waves 0,4 consume (w+2, higher j)
    if (!(w & 1) && (w & 2)) {
        const int s = w >> 2;
        #pragma unroll
        for (int t = 0; t < 16; ++t) { sbd[s][t][lane] = bd[t]; sbi[s][t][lane] = (unsigned short)bi[t]; }
    }
    __syncthreads();
    if (!(w & 3)) {
        const int s = w >> 2;
        #pragma unroll
        for (int t = 0; t < 16; ++t) insert16(bd, bi, sbd[s][t][lane], (int)sbi[s][t][lane]);
    }
    __syncthreads();
    // Round C: wave 4 publishes; wave 0 consumes (higher j)
    if (w == 4) {
        #pragma unroll
        for (int t = 0; t < 16; ++t) { sbd[0][t][lane] = bd[t]; sbi[0][t][lane] = (unsigned short)bi[t]; }
    }
    __syncthreads();
    if (w == 0) {
        #pragma unroll
        for (int t = 0; t < 16; ++t) insert16(bd, bi, sbd[0][t][lane], (int)sbi[0][t][lane]);
        unsigned short* o = knn + ((((size_t)b << 12) + i) << 4);
        #pragma unroll
        for (int t = 0; t < 16; ++t) o[t] = (unsigned short)bi[t];
    }
}

// Fused gather + GEMM(bf16 MFMA) + BN + ReLU + max-over-K.
// Wave handles 2 points; M-tile(16) = the 16 neighbors of one point, N = 128 outputs.
__global__ __launch_bounds__(256) void gemm_kernel(
    const short* __restrict__ xTb, const short* __restrict__ Wb,
    const unsigned short* __restrict__ knn,
    const float* __restrict__ scale, const float* __restrict__ bias,
    float* __restrict__ out)
{
    const int lane = threadIdx.x & 63;
    const int wid  = threadIdx.x >> 6;
    const int b    = blockIdx.x >> 9;            // N/8 = 512 groups per batch
    const int ng   = blockIdx.x & 511;
    const int n0   = ng * 8 + wid * 2;           // this wave's two points
    const int kl   = lane & 15;                  // A: m-index = neighbor k; B: n-index = out ch
    const int c0   = (lane >> 4) * 8;            // k-dim sub-offset within 32-chunk

    int rowoff[2];
    #pragma unroll
    for (int p = 0; p < 2; ++p) {
        const int n = n0 + p;
        const int r = (int)knn[(((size_t)b * NPTS + n) << 4) + kl];
        rowoff[p] = (b * NPTS + r) * CCH;        // element offset into xTb
    }

    const f32x4 zero = {0.f, 0.f, 0.f, 0.f};
    f32x4 acc[2][8];
    #pragma unroll
    for (int p = 0; p < 2; ++p)
        #pragma unroll
        for (int t = 0; t < 8; ++t) acc[p][t] = zero;

    #pragma unroll
    for (int kk = 0; kk < 4; ++kk) {             // K = 128 channels, 32 per MFMA
        const int cb = kk * 32 + c0;
        bf16x8 a0 = *(const bf16x8*)(xTb + rowoff[0] + cb);
        bf16x8 a1 = *(const bf16x8*)(xTb + rowoff[1] + cb);
        #pragma unroll
        for (int t = 0; t < 8; ++t) {
            const bf16x8 bf = *(const bf16x8*)(Wb + (t * 16 + kl) * CCH + cb);
            acc[0][t] = __builtin_amdgcn_mfma_f32_16x16x32_bf16(a0, bf, acc[0][t], 0, 0, 0);
            acc[1][t] = __builtin_amdgcn_mfma_f32_16x16x32_bf16(a1, bf, acc[1][t], 0, 0, 0);
        }
    }

    // Epilogue: BN + ReLU + max over the 16 rows (= neighbors) of each tile.
    #pragma unroll
    for (int t = 0; t < 8; ++t) {
        const int o = t * 16 + kl;
        const float s  = scale[o];
        const float bb = bias[o];
        #pragma unroll
        for (int p = 0; p < 2; ++p) {
            const f32x4 v = acc[p][t];
            float mx = 0.f;                      // relu floor: max_k relu(y) = max(0, max_k y)
            #pragma unroll
            for (int r = 0; r < 4; ++r) mx = fmaxf(mx, v[r] * s + bb);
            mx = fmaxf(mx, __shfl_xor(mx, 16));
            mx = fmaxf(mx, __shfl_xor(mx, 32));
            if (lane < 16) out[(size_t)(b * CCH + o) * NPTS + (n0 + p)] = mx;
        }
    }
}

extern "C" void kernel_launch(void* const* d_in, const int* in_sizes, int n_in,
                              void* d_out, int out_size, void* d_ws, size_t ws_size,
                              hipStream_t stream)
{
    const float* xyz   = (const float*)d_in[0];
    const float* x     = (const float*)d_in[1];
    const float* W     = (const float*)d_in[2];
    const float* gamma = (const float*)d_in[3];
    const float* beta  = (const float*)d_in[4];
    const float* rmean = (const float*)d_in[5];
    const float* rvar  = (const float*)d_in[6];
    float* out = (float*)d_out;

    char* ws = (char*)d_ws;
    short*          xTb   = (short*)(ws);
    short*          Wb    = (short*)(ws + 8388608);
    float*          scale = (float*)(ws + 8421376);
    float*          bias  = (float*)(ws + 8421888);
    float4*         pts   = (float4*)(ws + 8422400);
    unsigned short* knn   = (unsigned short*)(ws + 8946688);

    transpose_kernel<<<BATCH * 64 * 2, 256, 0, stream>>>(x, xTb);
    small_prep_kernel<<<BATCH * NPTS / 256, 256, 0, stream>>>(
        xyz, W, gamma, beta, rmean, rvar, Wb, scale, bias, pts);
    knn_kernel<<<BATCH * (NPTS / 64), 512, 0, stream>>>(pts, knn);
    gemm_kernel<<<BATCH * (NPTS / 8), 256, 0, stream>>>(xTb, Wb, knn, scale, bias, out);
}